// Round 13
// baseline (292.144 us; speedup 1.0000x reference)
//
#include <hip/hip_runtime.h>
#include <cstdint>
#include <cstddef>

// ---------------- problem constants (fixed by setup_inputs; k==32 always) ----
constexpr int B_SZ  = 256;
constexpr int T_SZ  = 8;
constexpr int DIN   = 768;
constexpr int DSAE  = 8192;
constexpr int KSEL  = 32;
constexpr int NROWS = B_SZ * T_SZ;        // 2048 (row r = b*T + t)
constexpr int CAND_CAP = 64;
constexpr int RCAP  = 32;                 // boundary-window capacity
constexpr float EPS_W = 3.2e-4f;          // ~8+ sigma of pre err (rne-A, rne-B)
constexpr int NSK   = DIN / 32;           // 24 K-steps

// ---------------- workspace layout (units: 4-byte words) ---------------------
// Packed-B (encoder, early) and W_dec-bf16 (decoder, late) OVERLAY the same
// region: packed-B is dead after k_encoder; k_transpose runs after it.
constexpr size_t XC_SZ    = (size_t)NROWS * DIN;            // 1,572,864 w (6 MB)
constexpr size_t OFF_XC   = 0;
constexpr size_t OFF_XCP  = OFF_XC + XC_SZ;                 // packed bf16 xc
constexpr size_t XCP_W    = XC_SZ / 2;                      // 786,432 w (3 MB)
constexpr size_t OFF_SIDX = OFF_XCP + XCP_W;
constexpr size_t OFF_SVAL = OFF_SIDX + (size_t)NROWS * KSEL;
constexpr size_t OFF_BIG  = OFF_SVAL + (size_t)NROWS * KSEL;
constexpr size_t BIG_W    = (size_t)T_SZ * DSAE * DIN / 2;  // 25,165,824 w (100.6 MB)
constexpr size_t WS_FAST_WORDS = OFF_BIG + BIG_W;           // ~110 MB

typedef short bf16x8 __attribute__((ext_vector_type(8)));  // 8 bf16 = 4 VGPR
typedef float f32x4  __attribute__((ext_vector_type(4)));

// RNE fp32 -> bf16 (16-bit result in low bits)
__device__ inline unsigned rne1(float x) {
  unsigned u = __float_as_uint(x);
  return (u + 0x7FFFu + ((u >> 16) & 1u)) >> 16;
}
__device__ inline float bf16tof(unsigned short v) {
  return __uint_as_float((unsigned)v << 16);
}

// ---------------- tiny init --------------------------------------------------
__global__ void k_zero(float* p) { *p = 0.f; }

// ---------------- xc = x - b_dec ; also emit FRAGMENT-PACKED bf16 copy -------
// Packed-A layout (bytes): unit (gm,t,s) of 1 KB at ((gm*8+t)*24+s)*1024,
// lane l's 16 B at +l*16 holding rows b=gm*16+(l&15), k=s*32+(l>>4)*8 ..+8.
__global__ __launch_bounds__(256) void k_xc(const float* __restrict__ x,
                                            const float* __restrict__ bdec,
                                            float* __restrict__ xc,
                                            unsigned short* __restrict__ xcp) {
  const int c = blockIdx.x * 256 + threadIdx.x;   // 0 .. 196607
  const int lane = c & 63;
  const int u = c >> 6;
  const int s  = u % NSK;
  const int tt = (u / NSK) & (T_SZ - 1);
  const int gm = u / (NSK * T_SZ);                // 0..15
  const int b  = gm * 16 + (lane & 15);
  const int k0 = s * 32 + (lane >> 4) * 8;
  const size_t rowOff = ((size_t)(b * T_SZ + tt)) * DIN + k0;
  float4 v0 = *(const float4*)(x + rowOff);
  float4 v1 = *(const float4*)(x + rowOff + 4);
  float4 d0 = *(const float4*)(bdec + tt * DIN + k0);
  float4 d1 = *(const float4*)(bdec + tt * DIN + k0 + 4);
  v0.x -= d0.x; v0.y -= d0.y; v0.z -= d0.z; v0.w -= d0.w;
  v1.x -= d1.x; v1.y -= d1.y; v1.z -= d1.z; v1.w -= d1.w;
  *(float4*)(xc + rowOff) = v0;
  *(float4*)(xc + rowOff + 4) = v1;
  uint4 p;
  p.x = rne1(v0.x) | (rne1(v0.y) << 16);
  p.y = rne1(v0.z) | (rne1(v0.w) << 16);
  p.z = rne1(v1.x) | (rne1(v1.y) << 16);
  p.w = rne1(v1.z) | (rne1(v1.w) << 16);
  *(uint4*)(xcp + (size_t)c * 8) = p;
}

// ---------------- pack W_enc -> fragment-linear bf16 (v2) --------------------
// Block = one (t,g) unit: READS its 64 Wenc rows as 192 KB CONTIGUOUS
// (2 KB per wave-instruction), WRITES its own 96 KB packed region. Every
// 256 B output line is filled entirely by this block (h&15 and kc both
// block-local) -> L2 write-combines full lines; no cross-XCD partial-line RMW.
// 24 independent iters/thread, no LDS, no barriers (full MLP).
// (v1 read 128 B segments at 3 KB row-stride -> request-rate-bound ~105 us.)
__global__ __launch_bounds__(256) void k_packB(const float* __restrict__ Wenc,
                                               unsigned short* __restrict__ wp) {
  const int blk = blockIdx.x;                       // (t,g): 0..1023
  const int tid = threadIdx.x;
  const float* src = Wenc + (size_t)blk * 49152;    // 64 rows x 768 fp32
  unsigned short* dst = wp + (size_t)blk * 49152;   // 96 KB packed region
#pragma unroll 4
  for (int it = 0; it < 24; ++it) {
    const int F = it * 2048 + tid * 8;              // tile float idx (linear)
    float4 v0 = *(const float4*)(src + F);
    float4 v1 = *(const float4*)(src + F + 4);
    const int hl = F / 768;                         // local row 0..63
    const int k  = F - hl * 768;
    const int s  = k >> 5;
    const int kc = (k >> 3) & 3;
    const int ni = hl >> 4;
    const int lane_out = (hl & 15) + (kc << 4);
    uint4 p;
    p.x = rne1(v0.x) | (rne1(v0.y) << 16);
    p.y = rne1(v0.z) | (rne1(v0.w) << 16);
    p.z = rne1(v1.x) | (rne1(v1.y) << 16);
    p.w = rne1(v1.z) | (rne1(v1.w) << 16);
    *(uint4*)(dst + (size_t)(s * 4 + ni) * 512 + lane_out * 8) = p;
  }
}

// ---------------- encoder: pre = xc @ W_enc[t]^T + b_enc (bf16 MFMA) ---------
// r10 structure (the proven-fast one): both operands FRAGMENT-LINEAR; every
// hot-loop load is one global_load_dwordx4 covering 1 KB contiguous per wave.
// No LDS, no barriers, no conversion VALU. 4 waves/block, wave tile 64x64;
// grid 128x8 = 1024 blocks = 4/CU balanced; compiler pipelines the reg loads.
__global__ __launch_bounds__(256, 4) void k_encoder(const unsigned short* __restrict__ xcp,
                                                    const unsigned short* __restrict__ wp,
                                                    const float* __restrict__ benc,
                                                    float* __restrict__ pre) {
  const int g = blockIdx.x;
  const int t = blockIdx.y;
  const int tid = threadIdx.x;
  const int wm = tid >> 6, lane = tid & 63;
  const int l15 = lane & 15, kc = lane >> 4;

  // A: halfword addr ((gm*8+t)*24+s)*512 + lane*8, gm = wm*4+mi
  const unsigned short* aP =
      xcp + ((size_t)(wm * 4 * T_SZ + t) * NSK) * 512 + lane * 8;
  constexpr size_t A_MI = (size_t)T_SZ * NSK * 512;   // +1 gm (halfwords)
  // B: halfword addr (((t*128+g)*24+s)*4+ni)*512 + lane*8
  const unsigned short* bP =
      wp + ((size_t)(t * 128 + g) * NSK) * 4 * 512 + lane * 8;

  f32x4 acc[4][4] = {};
#pragma unroll 4
  for (int s = 0; s < NSK; ++s) {
    bf16x8 a[4], b[4];
#pragma unroll
    for (int mi = 0; mi < 4; ++mi)
      a[mi] = *(const bf16x8*)(aP + (size_t)s * 512 + mi * A_MI);
#pragma unroll
    for (int ni = 0; ni < 4; ++ni)
      b[ni] = *(const bf16x8*)(bP + (size_t)s * 2048 + ni * 512);
#pragma unroll
    for (int mi = 0; mi < 4; ++mi)
#pragma unroll
      for (int ni = 0; ni < 4; ++ni)
        acc[mi][ni] = __builtin_amdgcn_mfma_f32_16x16x32_bf16(
            a[mi], b[ni], acc[mi][ni], 0, 0, 0);
  }

  // epilogue: C/D layout col=lane&15, row=(lane>>4)*4+reg
#pragma unroll
  for (int ni = 0; ni < 4; ++ni) {
    const int col = g * 64 + ni * 16 + l15;
    const float bias = benc[(size_t)t * DSAE + col];
#pragma unroll
    for (int mi = 0; mi < 4; ++mi) {
      const int rbase = wm * 64 + mi * 16 + kc * 4;
#pragma unroll
      for (int j = 0; j < 4; ++j)
        pre[((size_t)(rbase + j) * T_SZ + t) * DSAE + col] = acc[mi][ni][j] + bias;
    }
  }
}

// ---------------- fused top-k select -----------------------------------------
__global__ __launch_bounds__(256) void k_select(const float* __restrict__ xc,
                                                const float* __restrict__ Wenc,
                                                const float* __restrict__ benc,
                                                float* u,   // pre in, u out (aliased)
                                                int* __restrict__ sel_idx,
                                                float* __restrict__ sel_val) {
  const int r = blockIdx.x, t = r & (T_SZ - 1);
  __shared__ float sp[DSAE];     // 32 KB
  __shared__ float redf[4], redf2[4];
  __shared__ int   redi[4];
  __shared__ float cv[CAND_CAP]; __shared__ int ci[CAND_CAP];
  __shared__ float sv[CAND_CAP]; __shared__ int si[CAND_CAP];
  __shared__ float rv[RCAP];     __shared__ int ri[RCAP];
  __shared__ double rd[RCAP];
  __shared__ double xd[DIN];     // 6 KB
  __shared__ int   s_n, s_nR, s_A, s_nW;
  const int tid = threadIdx.x, lane = tid & 63, w = tid >> 6;
  float* urow = u + (size_t)r * DSAE;

  // load row + moments
  float s1 = 0.f, s2 = 0.f;
  for (int sgm = 0; sgm < DSAE / 256; ++sgm) {
    float v = urow[tid + sgm * 256];
    sp[tid + sgm * 256] = v;
    s1 += v; s2 = fmaf(v, v, s2);
  }
  for (int off = 32; off; off >>= 1) {
    s1 += __shfl_down(s1, off); s2 += __shfl_down(s2, off);
  }
  if (lane == 0) { redf[w] = s1; redf2[w] = s2; }
  __syncthreads();
  const float mean = (redf[0] + redf[1] + redf[2] + redf[3]) * (1.f / DSAE);
  const float var  = (redf2[0] + redf2[1] + redf2[2] + redf2[3]) * (1.f / DSAE) - mean * mean;
  const float sd   = sqrtf(fmaxf(var, 1e-20f));

  auto countGE = [&](float th) -> int {
    int c = 0;
#pragma unroll
    for (int sgm = 0; sgm < DSAE / 256; ++sgm)
      c += (sp[tid + sgm * 256] >= th) ? 1 : 0;
    for (int off = 32; off; off >>= 1) c += __shfl_down(c, off);
    __syncthreads();               // protect redi reuse
    if (lane == 0) redi[w] = c;
    __syncthreads();
    return redi[0] + redi[1] + redi[2] + redi[3];
  };

  float tlo = mean + 2.0f * sd, thi = mean + 3.5f * sd;
  for (int it = 0; it < 8 && countGE(tlo) < KSEL; ++it) tlo -= sd;
  float th = mean + 2.52f * sd;    // Gaussian seed: tail ~48/8192
  int c = countGE(th);
  for (int it = 0; it < 24 && (c < KSEL || c > CAND_CAP); ++it) {
    if (c > CAND_CAP) tlo = th; else thi = th;
    th = 0.5f * (tlo + thi);
    c = countGE(th);
  }
  if (c < KSEL) { th = tlo; c = countGE(th); }   // tlo has count >= 32

  // collect candidates >= th
  if (tid == 0) s_n = 0;
  __syncthreads();
  for (int sgm = 0; sgm < DSAE / 256; ++sgm) {
    int i = tid + sgm * 256;
    float v = sp[i];
    if (v >= th) {
      int p = atomicAdd(&s_n, 1);
      if (p < CAND_CAP) { cv[p] = v; ci[p] = i; }
    }
  }
  __syncthreads();
  const int n = s_n < CAND_CAP ? s_n : CAND_CAP;

  // sort desc (rank by value; ties lower idx first)
  if (tid < n) {
    float v = cv[tid]; int id = ci[tid];
    int rk = 0;
    for (int j = 0; j < n; ++j) {
      float vj = cv[j];
      rk += (vj > v || (vj == v && ci[j] < id)) ? 1 : 0;
    }
    sv[rk] = v; si[rk] = id;
  }
  __syncthreads();

  const float v32 = sv[KSEL - 1];
  const float wlo = v32 - EPS_W, whi = v32 + EPS_W;
  if (tid == 0) {
    int A = 0;
    while (A < KSEL - 1 && sv[A] > whi) ++A;       // certainly-selected count
    s_A = A;
    int e = A;
    while (e < n && sv[e] >= wlo) ++e;             // window members in collection
    s_nW = e - A;
  }
  __syncthreads();
  const int A  = s_A;
  const int nW = s_nW < RCAP ? s_nW : RCAP;
  if (tid < nW) { rv[tid] = sv[A + tid]; ri[tid] = si[A + tid]; }
  if (tid == 0) s_nR = nW;
  __syncthreads();
  // append window members below collection threshold (rare)
  if (th > wlo) {
    for (int sgm = 0; sgm < DSAE / 256; ++sgm) {
      int i = tid + sgm * 256;
      float v = sp[i];
      if (v >= wlo && v < th) {
        int p = atomicAdd(&s_nR, 1);
        if (p < RCAP) { rv[p] = v; ri[p] = i; }
      }
    }
  }
  __syncthreads();
  const int nR = s_nR < RCAP ? s_nR : RCAP;

  // fp64 refinement of boundary members (membership order + exact values)
  if (nR >= 2) {
    for (int i = tid; i < DIN; i += 256) xd[i] = (double)xc[(size_t)r * DIN + i];
    __syncthreads();
    for (int j = w; j < nR; j += 4) {   // one wave per member
      const int h = ri[j];
      const float* wrow = Wenc + ((size_t)t * DSAE + h) * DIN;
      double s = 0.0;
#pragma unroll
      for (int ss = 0; ss < DIN / 64; ++ss)
        s += xd[lane + 64 * ss] * (double)wrow[lane + 64 * ss];
      for (int off = 32; off; off >>= 1) s += __shfl_down(s, off);
      if (lane == 0) rd[j] = s + (double)benc[(size_t)t * DSAE + h];
    }
  } else if (nR == 1) {
    if (tid == 0) rd[0] = (double)rv[0];   // membership certain; pre value fine
  }
  __syncthreads();

  // overwrite row with u = zeros + scattered relu values
  for (int sgm = 0; sgm < DSAE / 256; ++sgm) urow[tid + sgm * 256] = 0.f;
  __syncthreads();

  if (tid < A) {   // A-set: pre values (err ~3e-5, far under threshold)
    float val = fmaxf(sv[tid], 0.f);
    urow[si[tid]] = val;
    sel_idx[(size_t)r * KSEL + tid] = si[tid];
    sel_val[(size_t)r * KSEL + tid] = val;
  }
  const int need = KSEL - A;
  if (tid < nR) {  // R-set: top-(32-A) by fp64 (ties lower idx)
    double v = rd[tid]; int id = ri[tid];
    int rk = 0;
    for (int j = 0; j < nR; ++j) {
      double vj = rd[j];
      rk += (vj > v || (vj == v && ri[j] < id)) ? 1 : 0;
    }
    if (rk < need) {
      float val = fmaxf((float)v, 0.f);
      urow[id] = val;
      sel_idx[(size_t)r * KSEL + A + rk] = id;
      sel_val[(size_t)r * KSEL + A + rk] = val;
    }
  }
}

// ---------------- W_dec transpose: (T,DIN,DSAE) f32 -> (T,DSAE,DIN) bf16 -----
__global__ __launch_bounds__(256) void k_transpose(const float* __restrict__ W,
                                                   unsigned short* __restrict__ Wt) {
  __shared__ float s[32][33];
  const int t  = blockIdx.z;
  const int h0 = blockIdx.x * 32;
  const int d0 = blockIdx.y * 32;
  const int c  = threadIdx.x & 31, rr = threadIdx.x >> 5;  // 8 rows/pass
#pragma unroll
  for (int q = 0; q < 4; ++q) {
    int d = d0 + rr + q * 8;
    s[rr + q * 8][c] = W[((size_t)t * DIN + d) * DSAE + h0 + c];
  }
  __syncthreads();
#pragma unroll
  for (int q = 0; q < 4; ++q) {
    int h = h0 + rr + q * 8;
    Wt[((size_t)t * DSAE + h) * DIN + d0 + c] = (unsigned short)rne1(s[c][rr + q * 8]);
  }
}

// ---------------- sparse decoder + fused loss --------------------------------
template <bool TRANSPOSED>
__global__ __launch_bounds__(256) void k_decoder(const void* __restrict__ Wd_,
                                                 const float* __restrict__ x,
                                                 const float* __restrict__ bdec,
                                                 const int* __restrict__ sel_idx,
                                                 const float* __restrict__ sel_val,
                                                 float* __restrict__ xhat,
                                                 float* __restrict__ loss) {
  const int r = blockIdx.x, t = r & (T_SZ - 1);
  __shared__ int   si[KSEL];
  __shared__ float sv[KSEL];
  __shared__ float rbuf[4];
  const int tid = threadIdx.x;
  if (tid < KSEL) {
    si[tid] = sel_idx[(size_t)r * KSEL + tid] & (DSAE - 1);  // safety mask
    sv[tid] = sel_val[(size_t)r * KSEL + tid];
  }
  __syncthreads();

  float acc[3];
#pragma unroll
  for (int i = 0; i < 3; ++i) acc[i] = bdec[(size_t)t * DIN + tid + 256 * i];
#pragma unroll 4
  for (int j = 0; j < KSEL; ++j) {
    const int h = si[j];
    const float v = sv[j];
    if (TRANSPOSED) {
      const unsigned short* wrow =
          (const unsigned short*)Wd_ + ((size_t)t * DSAE + h) * DIN;
#pragma unroll
      for (int i = 0; i < 3; ++i)
        acc[i] = fmaf(v, bf16tof(wrow[tid + 256 * i]), acc[i]);
    } else {
      const float* Wd = (const float*)Wd_;
#pragma unroll
      for (int i = 0; i < 3; ++i)
        acc[i] = fmaf(v, Wd[((size_t)t * DIN + tid + 256 * i) * DSAE + h], acc[i]);
    }
  }
  float sq = 0.f;
#pragma unroll
  for (int i = 0; i < 3; ++i) {
    const int d = tid + 256 * i;
    const float xv = x[(size_t)r * DIN + d];
    xhat[(size_t)r * DIN + d] = acc[i];
    const float e = acc[i] - xv;
    sq = fmaf(e, e, sq);
  }
  for (int off = 32; off; off >>= 1) sq += __shfl_down(sq, off);
  if ((tid & 63) == 0) rbuf[tid >> 6] = sq;
  __syncthreads();
  if (tid == 0)
    atomicAdd(loss, (rbuf[0] + rbuf[1] + rbuf[2] + rbuf[3]) * (1.0f / NROWS));
}

// ---------------- host ------------------------------------------------------
extern "C" void kernel_launch(void* const* d_in, const int* in_sizes, int n_in,
                              void* d_out, int out_size, void* d_ws, size_t ws_size,
                              hipStream_t stream) {
  const float* x    = (const float*)d_in[0];
  const float* Wenc = (const float*)d_in[1];
  const float* benc = (const float*)d_in[2];
  const float* Wdec = (const float*)d_in[3];
  const float* bdec = (const float*)d_in[4];
  // d_in[5] is k (==32), baked in as KSEL.

  float* out  = (float*)d_out;
  float* loss = out;
  float* xhat = out + 1;
  float* u    = out + 1 + (size_t)NROWS * DIN;  // (B,T,DSAE) == rows r

  float*          wsf  = (float*)d_ws;
  float*          xc   = wsf + OFF_XC;
  unsigned short* xcp  = (unsigned short*)(wsf + OFF_XCP);
  int*            sidx = (int*)(wsf + OFF_SIDX);
  float*          sval = wsf + OFF_SVAL;
  unsigned short* big  = (unsigned short*)(wsf + OFF_BIG);  // wp, then wt
  const bool fast = ws_size >= WS_FAST_WORDS * sizeof(float);

  k_zero<<<1, 1, 0, stream>>>(loss);
  k_xc<<<NROWS * DIN / (256 * 8), 256, 0, stream>>>(x, bdec, xc, xcp);  // 768 blocks
  k_packB<<<T_SZ * 128, 256, 0, stream>>>(Wenc, big);                   // 1024 blocks
  k_encoder<<<dim3(DSAE / 64, T_SZ), 256, 0, stream>>>(xcp, big, benc, u);
  k_select<<<NROWS, 256, 0, stream>>>(xc, Wenc, benc, u, sidx, sval);
  if (fast) {
    k_transpose<<<dim3(DSAE / 32, DIN / 32, T_SZ), 256, 0, stream>>>(Wdec, big);
    k_decoder<true><<<NROWS, 256, 0, stream>>>(big, x, bdec, sidx, sval, xhat, loss);
  } else {
    k_decoder<false><<<NROWS, 256, 0, stream>>>(Wdec, x, bdec, sidx, sval, xhat, loss);
  }
}

// Round 14
// 282.080 us; speedup vs baseline: 1.0357x; 1.0357x over previous
//
#include <hip/hip_runtime.h>
#include <cstdint>
#include <cstddef>

// ---------------- problem constants (fixed by setup_inputs; k==32 always) ----
constexpr int B_SZ  = 256;
constexpr int T_SZ  = 8;
constexpr int DIN   = 768;
constexpr int DSAE  = 8192;
constexpr int KSEL  = 32;
constexpr int NROWS = B_SZ * T_SZ;        // 2048 (row r = b*T + t)
constexpr int CAND_CAP = 64;
constexpr int RCAP  = 32;                 // boundary-window capacity
constexpr float EPS_W = 3.2e-4f;          // ~7 sigma of pre err (trunc-B + rne-A)
constexpr int NSK   = DIN / 32;           // 24 K-steps

// ---------------- workspace layout (units: 4-byte words) ---------------------
constexpr size_t XC_SZ    = (size_t)NROWS * DIN;            // 1,572,864 w (6 MB)
constexpr size_t OFF_XC   = 0;
constexpr size_t OFF_XCP  = OFF_XC + XC_SZ;                 // packed bf16 xc
constexpr size_t XCP_W    = XC_SZ / 2;                      // 786,432 w (3 MB)
constexpr size_t OFF_SIDX = OFF_XCP + XCP_W;
constexpr size_t OFF_SVAL = OFF_SIDX + (size_t)NROWS * KSEL;
constexpr size_t OFF_BIG  = OFF_SVAL + (size_t)NROWS * KSEL;
constexpr size_t BIG_W    = (size_t)T_SZ * DSAE * DIN / 2;  // 25,165,824 w (100.6 MB)
constexpr size_t WS_FAST_WORDS = OFF_BIG + BIG_W;           // ~110 MB

typedef short bf16x8 __attribute__((ext_vector_type(8)));  // 8 bf16 = 4 VGPR
typedef float f32x4  __attribute__((ext_vector_type(4)));

// RNE fp32 -> bf16 (16-bit result in low bits)
__device__ inline unsigned rne1(float x) {
  unsigned u = __float_as_uint(x);
  return (u + 0x7FFFu + ((u >> 16) & 1u)) >> 16;
}
__device__ inline float bf16tof(unsigned short v) {
  return __uint_as_float((unsigned)v << 16);
}
// truncating pack: (hi16(b)<<16) | hi16(a)
__device__ inline unsigned packtr(float a, float b) {
  return (__float_as_uint(a) >> 16) | (__float_as_uint(b) & 0xFFFF0000u);
}

// async global->LDS, 16 bytes, per-lane global source, linear LDS dest
__device__ inline void gload_lds16(const void* g, void* l) {
  __builtin_amdgcn_global_load_lds(
      (const __attribute__((address_space(1))) void*)g,
      (__attribute__((address_space(3))) void*)l, 16, 0, 0);
}

// ---------------- tiny init --------------------------------------------------
__global__ void k_zero(float* p) { *p = 0.f; }

// ---------------- xc = x - b_dec ; also emit FRAGMENT-PACKED bf16 copy -------
// Packed-A layout (bytes): unit (gm,t,s) of 1 KB at ((gm*8+t)*24+s)*1024,
// lane l's 16 B at +l*16 holding rows b=gm*16+(l&15), k=s*32+(l>>4)*8 ..+8.
__global__ __launch_bounds__(256) void k_xc(const float* __restrict__ x,
                                            const float* __restrict__ bdec,
                                            float* __restrict__ xc,
                                            unsigned short* __restrict__ xcp) {
  const int c = blockIdx.x * 256 + threadIdx.x;   // 0 .. 196607
  const int lane = c & 63;
  const int u = c >> 6;
  const int s  = u % NSK;
  const int tt = (u / NSK) & (T_SZ - 1);
  const int gm = u / (NSK * T_SZ);                // 0..15
  const int b  = gm * 16 + (lane & 15);
  const int k0 = s * 32 + (lane >> 4) * 8;
  const size_t rowOff = ((size_t)(b * T_SZ + tt)) * DIN + k0;
  float4 v0 = *(const float4*)(x + rowOff);
  float4 v1 = *(const float4*)(x + rowOff + 4);
  float4 d0 = *(const float4*)(bdec + tt * DIN + k0);
  float4 d1 = *(const float4*)(bdec + tt * DIN + k0 + 4);
  v0.x -= d0.x; v0.y -= d0.y; v0.z -= d0.z; v0.w -= d0.w;
  v1.x -= d1.x; v1.y -= d1.y; v1.z -= d1.z; v1.w -= d1.w;
  *(float4*)(xc + rowOff) = v0;
  *(float4*)(xc + rowOff + 4) = v1;
  uint4 p;
  p.x = rne1(v0.x) | (rne1(v0.y) << 16);
  p.y = rne1(v0.z) | (rne1(v0.w) << 16);
  p.z = rne1(v1.x) | (rne1(v1.y) << 16);
  p.w = rne1(v1.z) | (rne1(v1.w) << 16);
  *(uint4*)(xcp + (size_t)c * 8) = p;
}

// ---------------- encoder: pre = xc @ W_enc[t]^T + b_enc (bf16 MFMA) ---------
// Direct-consume, fully-contiguous staging: block = 16 consecutive h-rows x
// full K of W_enc[t] = ONE 48 KB CONTIGUOUS region. Staged via 12 gload_lds
// per thread (per-lane src = linear + slot-swizzle within 128-B chunks; T21
// involution: slot ^= row&7 at 16-B granularity; rows at 3072 B = multiple of
// 128 -> row-stable). ONE __syncthreads per block (single vmcnt drain,
// amortized over 24 K-steps -- unlike the per-step drains of r4-r9).
// Then 24 MFMA steps: B-frag = 2 swizzled ds_read_b128 + trunc-pack; A-frags
// from fragment-packed xcp (3 MB, L2-hot, 1 KB linear loads).
// 48 KB LDS -> 3 blocks/CU: compute << stage, so each CU streams Wenc at
// linear rate continuously. Grid 512x8 = 4096 blocks = 16/CU balanced.
// No packB: Wenc read exactly once, zero pack traffic.
__global__ __launch_bounds__(256, 3) void k_encoder(const unsigned short* __restrict__ xcp,
                                                    const float* __restrict__ Wenc,
                                                    const float* __restrict__ benc,
                                                    float* __restrict__ pre) {
  __shared__ __align__(16) float Bs[16 * DIN];   // 48 KB fp32, slot-swizzled
  const int g = blockIdx.x;                      // 0..511 -> cols g*16..+16
  const int t = blockIdx.y;
  const int tid = threadIdx.x;
  const int wm = tid >> 6, lane = tid & 63;
  const int l15 = lane & 15, kc = lane >> 4;

  // ---- stage: 48 KB contiguous global (16 rows x 3072 B, rows adjacent) ----
  const char* tileBase = (const char*)(Wenc + ((size_t)t * DSAE + g * 16) * DIN);
  char* bsb = (char*)&Bs[0];
#pragma unroll
  for (int it = 0; it < 12; ++it) {
    const int L = it * 4096 + tid * 16;          // linear LDS byte pos
    const int row = L / 3072;                    // 0..15 (chunk-stable)
    const int inRow = L - row * 3072;
    const int inRowSwz = (inRow & ~0x70) | (((((inRow >> 4) & 7) ^ (row & 7))) << 4);
    gload_lds16(tileBase + row * 3072 + inRowSwz, bsb + L);
  }
  __syncthreads();                               // single drain per block

  // ---- compute: 24 K-steps; A packed-linear, B = 2 swizzled b128 + trunc ---
  const unsigned short* aP =
      xcp + ((size_t)(wm * 4 * T_SZ + t) * NSK) * 512 + lane * 8;
  constexpr size_t A_MI = (size_t)T_SZ * NSK * 512;   // +16 b-rows (halfwords)
  const int rowF = l15;
  const int sw = rowF & 7;
  const int bOff0 = rowF * 3072 + (((kc * 2 + 0) ^ sw) << 4);
  const int bOff1 = rowF * 3072 + (((kc * 2 + 1) ^ sw) << 4);

  f32x4 acc[4] = {};
#pragma unroll 4
  for (int s = 0; s < NSK; ++s) {
    bf16x8 a[4];
#pragma unroll
    for (int mi = 0; mi < 4; ++mi)
      a[mi] = *(const bf16x8*)(aP + (size_t)s * 512 + mi * A_MI);
    f32x4 f0 = *(const f32x4*)(bsb + bOff0 + s * 128);
    f32x4 f1 = *(const f32x4*)(bsb + bOff1 + s * 128);
    union { uint32_t w[4]; bf16x8 h; } cv;
    cv.w[0] = packtr(f0.x, f0.y); cv.w[1] = packtr(f0.z, f0.w);
    cv.w[2] = packtr(f1.x, f1.y); cv.w[3] = packtr(f1.z, f1.w);
#pragma unroll
    for (int mi = 0; mi < 4; ++mi)
      acc[mi] = __builtin_amdgcn_mfma_f32_16x16x32_bf16(a[mi], cv.h, acc[mi], 0, 0, 0);
  }

  // epilogue: C/D layout col=lane&15, row=(lane>>4)*4+reg
  const int col = g * 16 + l15;
  const float bias = benc[(size_t)t * DSAE + col];
#pragma unroll
  for (int mi = 0; mi < 4; ++mi) {
    const int rbase = wm * 64 + mi * 16 + kc * 4;
#pragma unroll
    for (int j = 0; j < 4; ++j)
      pre[((size_t)(rbase + j) * T_SZ + t) * DSAE + col] = acc[mi][j] + bias;
  }
}

// ---------------- fused top-k select -----------------------------------------
__global__ __launch_bounds__(256) void k_select(const float* __restrict__ xc,
                                                const float* __restrict__ Wenc,
                                                const float* __restrict__ benc,
                                                float* u,   // pre in, u out (aliased)
                                                int* __restrict__ sel_idx,
                                                float* __restrict__ sel_val) {
  const int r = blockIdx.x, t = r & (T_SZ - 1);
  __shared__ float sp[DSAE];     // 32 KB
  __shared__ float redf[4], redf2[4];
  __shared__ int   redi[4];
  __shared__ float cv[CAND_CAP]; __shared__ int ci[CAND_CAP];
  __shared__ float sv[CAND_CAP]; __shared__ int si[CAND_CAP];
  __shared__ float rv[RCAP];     __shared__ int ri[RCAP];
  __shared__ double rd[RCAP];
  __shared__ double xd[DIN];     // 6 KB
  __shared__ int   s_n, s_nR, s_A, s_nW;
  const int tid = threadIdx.x, lane = tid & 63, w = tid >> 6;
  float* urow = u + (size_t)r * DSAE;

  // load row + moments
  float s1 = 0.f, s2 = 0.f;
  for (int sgm = 0; sgm < DSAE / 256; ++sgm) {
    float v = urow[tid + sgm * 256];
    sp[tid + sgm * 256] = v;
    s1 += v; s2 = fmaf(v, v, s2);
  }
  for (int off = 32; off; off >>= 1) {
    s1 += __shfl_down(s1, off); s2 += __shfl_down(s2, off);
  }
  if (lane == 0) { redf[w] = s1; redf2[w] = s2; }
  __syncthreads();
  const float mean = (redf[0] + redf[1] + redf[2] + redf[3]) * (1.f / DSAE);
  const float var  = (redf2[0] + redf2[1] + redf2[2] + redf2[3]) * (1.f / DSAE) - mean * mean;
  const float sd   = sqrtf(fmaxf(var, 1e-20f));

  auto countGE = [&](float th) -> int {
    int c = 0;
#pragma unroll
    for (int sgm = 0; sgm < DSAE / 256; ++sgm)
      c += (sp[tid + sgm * 256] >= th) ? 1 : 0;
    for (int off = 32; off; off >>= 1) c += __shfl_down(c, off);
    __syncthreads();               // protect redi reuse
    if (lane == 0) redi[w] = c;
    __syncthreads();
    return redi[0] + redi[1] + redi[2] + redi[3];
  };

  float tlo = mean + 2.0f * sd, thi = mean + 3.5f * sd;
  for (int it = 0; it < 8 && countGE(tlo) < KSEL; ++it) tlo -= sd;
  float th = mean + 2.52f * sd;    // Gaussian seed: tail ~48/8192
  int c = countGE(th);
  for (int it = 0; it < 24 && (c < KSEL || c > CAND_CAP); ++it) {
    if (c > CAND_CAP) tlo = th; else thi = th;
    th = 0.5f * (tlo + thi);
    c = countGE(th);
  }
  if (c < KSEL) { th = tlo; c = countGE(th); }   // tlo has count >= 32

  // collect candidates >= th
  if (tid == 0) s_n = 0;
  __syncthreads();
  for (int sgm = 0; sgm < DSAE / 256; ++sgm) {
    int i = tid + sgm * 256;
    float v = sp[i];
    if (v >= th) {
      int p = atomicAdd(&s_n, 1);
      if (p < CAND_CAP) { cv[p] = v; ci[p] = i; }
    }
  }
  __syncthreads();
  const int n = s_n < CAND_CAP ? s_n : CAND_CAP;

  // sort desc (rank by value; ties lower idx first)
  if (tid < n) {
    float v = cv[tid]; int id = ci[tid];
    int rk = 0;
    for (int j = 0; j < n; ++j) {
      float vj = cv[j];
      rk += (vj > v || (vj == v && ci[j] < id)) ? 1 : 0;
    }
    sv[rk] = v; si[rk] = id;
  }
  __syncthreads();

  const float v32 = sv[KSEL - 1];
  const float wlo = v32 - EPS_W, whi = v32 + EPS_W;
  if (tid == 0) {
    int A = 0;
    while (A < KSEL - 1 && sv[A] > whi) ++A;       // certainly-selected count
    s_A = A;
    int e = A;
    while (e < n && sv[e] >= wlo) ++e;             // window members in collection
    s_nW = e - A;
  }
  __syncthreads();
  const int A  = s_A;
  const int nW = s_nW < RCAP ? s_nW : RCAP;
  if (tid < nW) { rv[tid] = sv[A + tid]; ri[tid] = si[A + tid]; }
  if (tid == 0) s_nR = nW;
  __syncthreads();
  // append window members below collection threshold (rare)
  if (th > wlo) {
    for (int sgm = 0; sgm < DSAE / 256; ++sgm) {
      int i = tid + sgm * 256;
      float v = sp[i];
      if (v >= wlo && v < th) {
        int p = atomicAdd(&s_nR, 1);
        if (p < RCAP) { rv[p] = v; ri[p] = i; }
      }
    }
  }
  __syncthreads();
  const int nR = s_nR < RCAP ? s_nR : RCAP;

  // fp64 refinement of boundary members (membership order + exact values)
  if (nR >= 2) {
    for (int i = tid; i < DIN; i += 256) xd[i] = (double)xc[(size_t)r * DIN + i];
    __syncthreads();
    for (int j = w; j < nR; j += 4) {   // one wave per member
      const int h = ri[j];
      const float* wrow = Wenc + ((size_t)t * DSAE + h) * DIN;
      double s = 0.0;
#pragma unroll
      for (int ss = 0; ss < DIN / 64; ++ss)
        s += xd[lane + 64 * ss] * (double)wrow[lane + 64 * ss];
      for (int off = 32; off; off >>= 1) s += __shfl_down(s, off);
      if (lane == 0) rd[j] = s + (double)benc[(size_t)t * DSAE + h];
    }
  } else if (nR == 1) {
    if (tid == 0) rd[0] = (double)rv[0];   // membership certain; pre value fine
  }
  __syncthreads();

  // overwrite row with u = zeros + scattered relu values
  for (int sgm = 0; sgm < DSAE / 256; ++sgm) urow[tid + sgm * 256] = 0.f;
  __syncthreads();

  if (tid < A) {   // A-set: pre values (err ~4e-5, far under threshold)
    float val = fmaxf(sv[tid], 0.f);
    urow[si[tid]] = val;
    sel_idx[(size_t)r * KSEL + tid] = si[tid];
    sel_val[(size_t)r * KSEL + tid] = val;
  }
  const int need = KSEL - A;
  if (tid < nR) {  // R-set: top-(32-A) by fp64 (ties lower idx)
    double v = rd[tid]; int id = ri[tid];
    int rk = 0;
    for (int j = 0; j < nR; ++j) {
      double vj = rd[j];
      rk += (vj > v || (vj == v && ri[j] < id)) ? 1 : 0;
    }
    if (rk < need) {
      float val = fmaxf((float)v, 0.f);
      urow[id] = val;
      sel_idx[(size_t)r * KSEL + A + rk] = id;
      sel_val[(size_t)r * KSEL + A + rk] = val;
    }
  }
}

// ---------------- W_dec transpose: (T,DIN,DSAE) f32 -> (T,DSAE,DIN) bf16 -----
__global__ __launch_bounds__(256) void k_transpose(const float* __restrict__ W,
                                                   unsigned short* __restrict__ Wt) {
  __shared__ float s[32][33];
  const int t  = blockIdx.z;
  const int h0 = blockIdx.x * 32;
  const int d0 = blockIdx.y * 32;
  const int c  = threadIdx.x & 31, rr = threadIdx.x >> 5;  // 8 rows/pass
#pragma unroll
  for (int q = 0; q < 4; ++q) {
    int d = d0 + rr + q * 8;
    s[rr + q * 8][c] = W[((size_t)t * DIN + d) * DSAE + h0 + c];
  }
  __syncthreads();
#pragma unroll
  for (int q = 0; q < 4; ++q) {
    int h = h0 + rr + q * 8;
    Wt[((size_t)t * DSAE + h) * DIN + d0 + c] = (unsigned short)rne1(s[c][rr + q * 8]);
  }
}

// ---------------- sparse decoder + fused loss --------------------------------
template <bool TRANSPOSED>
__global__ __launch_bounds__(256) void k_decoder(const void* __restrict__ Wd_,
                                                 const float* __restrict__ x,
                                                 const float* __restrict__ bdec,
                                                 const int* __restrict__ sel_idx,
                                                 const float* __restrict__ sel_val,
                                                 float* __restrict__ xhat,
                                                 float* __restrict__ loss) {
  const int r = blockIdx.x, t = r & (T_SZ - 1);
  __shared__ int   si[KSEL];
  __shared__ float sv[KSEL];
  __shared__ float rbuf[4];
  const int tid = threadIdx.x;
  if (tid < KSEL) {
    si[tid] = sel_idx[(size_t)r * KSEL + tid] & (DSAE - 1);  // safety mask
    sv[tid] = sel_val[(size_t)r * KSEL + tid];
  }
  __syncthreads();

  float acc[3];
#pragma unroll
  for (int i = 0; i < 3; ++i) acc[i] = bdec[(size_t)t * DIN + tid + 256 * i];
#pragma unroll 4
  for (int j = 0; j < KSEL; ++j) {
    const int h = si[j];
    const float v = sv[j];
    if (TRANSPOSED) {
      const unsigned short* wrow =
          (const unsigned short*)Wd_ + ((size_t)t * DSAE + h) * DIN;
#pragma unroll
      for (int i = 0; i < 3; ++i)
        acc[i] = fmaf(v, bf16tof(wrow[tid + 256 * i]), acc[i]);
    } else {
      const float* Wd = (const float*)Wd_;
#pragma unroll
      for (int i = 0; i < 3; ++i)
        acc[i] = fmaf(v, Wd[((size_t)t * DIN + tid + 256 * i) * DSAE + h], acc[i]);
    }
  }
  float sq = 0.f;
#pragma unroll
  for (int i = 0; i < 3; ++i) {
    const int d = tid + 256 * i;
    const float xv = x[(size_t)r * DIN + d];
    xhat[(size_t)r * DIN + d] = acc[i];
    const float e = acc[i] - xv;
    sq = fmaf(e, e, sq);
  }
  for (int off = 32; off; off >>= 1) sq += __shfl_down(sq, off);
  if ((tid & 63) == 0) rbuf[tid >> 6] = sq;
  __syncthreads();
  if (tid == 0)
    atomicAdd(loss, (rbuf[0] + rbuf[1] + rbuf[2] + rbuf[3]) * (1.0f / NROWS));
}

// ---------------- host ------------------------------------------------------
extern "C" void kernel_launch(void* const* d_in, const int* in_sizes, int n_in,
                              void* d_out, int out_size, void* d_ws, size_t ws_size,
                              hipStream_t stream) {
  const float* x    = (const float*)d_in[0];
  const float* Wenc = (const float*)d_in[1];
  const float* benc = (const float*)d_in[2];
  const float* Wdec = (const float*)d_in[3];
  const float* bdec = (const float*)d_in[4];
  // d_in[5] is k (==32), baked in as KSEL.

  float* out  = (float*)d_out;
  float* loss = out;
  float* xhat = out + 1;
  float* u    = out + 1 + (size_t)NROWS * DIN;  // (B,T,DSAE) == rows r

  float*          wsf  = (float*)d_ws;
  float*          xc   = wsf + OFF_XC;
  unsigned short* xcp  = (unsigned short*)(wsf + OFF_XCP);
  int*            sidx = (int*)(wsf + OFF_SIDX);
  float*          sval = wsf + OFF_SVAL;
  unsigned short* big  = (unsigned short*)(wsf + OFF_BIG);  // wt (decoder)
  const bool fast = ws_size >= WS_FAST_WORDS * sizeof(float);

  k_zero<<<1, 1, 0, stream>>>(loss);
  k_xc<<<NROWS * DIN / (256 * 8), 256, 0, stream>>>(x, bdec, xc, xcp);  // 768 blocks
  k_encoder<<<dim3(DSAE / 16, T_SZ), 256, 0, stream>>>(xcp, Wenc, benc, u);
  k_select<<<NROWS, 256, 0, stream>>>(xc, Wenc, benc, u, sidx, sval);
  if (fast) {
    k_transpose<<<dim3(DSAE / 32, DIN / 32, T_SZ), 256, 0, stream>>>(Wdec, big);
    k_decoder<true><<<NROWS, 256, 0, stream>>>(big, x, bdec, sidx, sval, xhat, loss);
  } else {
    k_decoder<false><<<NROWS, 256, 0, stream>>>(Wdec, x, bdec, sidx, sval, xhat, loss);
  }
}

// Round 15
// 276.883 us; speedup vs baseline: 1.0551x; 1.0188x over previous
//
#include <hip/hip_runtime.h>
#include <cstdint>
#include <cstddef>

// ---------------- problem constants (fixed by setup_inputs; k==32 always) ----
constexpr int B_SZ  = 256;
constexpr int T_SZ  = 8;
constexpr int DIN   = 768;
constexpr int DSAE  = 8192;
constexpr int KSEL  = 32;
constexpr int NROWS = B_SZ * T_SZ;        // 2048 (row r = b*T + t)
constexpr int CAND_CAP = 64;              // slow-path collection cap
constexpr int CFCAP = 128;                // fused-candidate cap
constexpr int RCAP  = 32;                 // boundary-window capacity
constexpr float EPS_W = 3.2e-4f;          // ~7 sigma of pre err (trunc-B + rne-A)
constexpr int NSK   = DIN / 32;           // 24 K-steps
// tau = 2.35 * |xc_row| * (1/1024)/sqrt(3): collection threshold, lambda~77
constexpr float TAU_C = 1.324943e-3f;

// ---------------- workspace layout (units: 4-byte words) ---------------------
constexpr size_t XC_SZ    = (size_t)NROWS * DIN;            // 1,572,864 w
constexpr size_t OFF_XC   = 0;
constexpr size_t OFF_XCP  = OFF_XC + XC_SZ;                 // packed bf16 xc
constexpr size_t XCP_W    = XC_SZ / 2;
constexpr size_t OFF_SIDX = OFF_XCP + XCP_W;
constexpr size_t OFF_SVAL = OFF_SIDX + (size_t)NROWS * KSEL;
constexpr size_t OFF_TAU  = OFF_SVAL + (size_t)NROWS * KSEL;
constexpr size_t OFF_CCNT = OFF_TAU + NROWS;
constexpr size_t OFF_CIDX = OFF_CCNT + NROWS;
constexpr size_t OFF_CVAL = OFF_CIDX + (size_t)NROWS * CFCAP;
constexpr size_t WS_WORDS = OFF_CVAL + (size_t)NROWS * CFCAP;   // ~12 MB

typedef short bf16x8 __attribute__((ext_vector_type(8)));  // 8 bf16 = 4 VGPR
typedef float f32x4  __attribute__((ext_vector_type(4)));

__device__ inline unsigned rne1(float x) {
  unsigned u = __float_as_uint(x);
  return (u + 0x7FFFu + ((u >> 16) & 1u)) >> 16;
}
__device__ inline unsigned packtr(float a, float b) {
  return (__float_as_uint(a) >> 16) | (__float_as_uint(b) & 0xFFFF0000u);
}
__device__ inline void gload_lds16(const void* g, void* l) {
  __builtin_amdgcn_global_load_lds(
      (const __attribute__((address_space(1))) void*)g,
      (__attribute__((address_space(3))) void*)l, 16, 0, 0);
}

// ---------------- xc = x - b_dec ; also emit FRAGMENT-PACKED bf16 copy -------
__global__ __launch_bounds__(256) void k_xc(const float* __restrict__ x,
                                            const float* __restrict__ bdec,
                                            float* __restrict__ xc,
                                            unsigned short* __restrict__ xcp) {
  const int c = blockIdx.x * 256 + threadIdx.x;   // 0 .. 196607
  const int lane = c & 63;
  const int u = c >> 6;
  const int s  = u % NSK;
  const int tt = (u / NSK) & (T_SZ - 1);
  const int gm = u / (NSK * T_SZ);                // 0..15
  const int b  = gm * 16 + (lane & 15);
  const int k0 = s * 32 + (lane >> 4) * 8;
  const size_t rowOff = ((size_t)(b * T_SZ + tt)) * DIN + k0;
  float4 v0 = *(const float4*)(x + rowOff);
  float4 v1 = *(const float4*)(x + rowOff + 4);
  float4 d0 = *(const float4*)(bdec + tt * DIN + k0);
  float4 d1 = *(const float4*)(bdec + tt * DIN + k0 + 4);
  v0.x -= d0.x; v0.y -= d0.y; v0.z -= d0.z; v0.w -= d0.w;
  v1.x -= d1.x; v1.y -= d1.y; v1.z -= d1.z; v1.w -= d1.w;
  *(float4*)(xc + rowOff) = v0;
  *(float4*)(xc + rowOff + 4) = v1;
  uint4 p;
  p.x = rne1(v0.x) | (rne1(v0.y) << 16);
  p.y = rne1(v0.z) | (rne1(v0.w) << 16);
  p.z = rne1(v1.x) | (rne1(v1.y) << 16);
  p.w = rne1(v1.z) | (rne1(v1.w) << 16);
  *(uint4*)(xcp + (size_t)c * 8) = p;
}

// ---------------- tau per row + zero ccnt/loss -------------------------------
__global__ __launch_bounds__(256) void k_tau(const float* __restrict__ xc,
                                             float* __restrict__ tau,
                                             int* __restrict__ ccnt,
                                             float* __restrict__ loss) {
  const int tid = threadIdx.x, lane = tid & 63, w = tid >> 6;
  if (blockIdx.x < 8) ccnt[blockIdx.x * 256 + tid] = 0;
  if (blockIdx.x == 0 && tid == 0) *loss = 0.f;
  const int r = blockIdx.x * 4 + w;               // 512 blocks x 4 rows
  float s = 0.f;
#pragma unroll
  for (int ld = 0; ld < 3; ++ld) {
    float4 v = *(const float4*)(xc + (size_t)r * DIN + ld * 256 + lane * 4);
    s = fmaf(v.x, v.x, fmaf(v.y, v.y, fmaf(v.z, v.z, fmaf(v.w, v.w, s))));
  }
  for (int off = 32; off; off >>= 1) s += __shfl_down(s, off);
  if (lane == 0) tau[r] = TAU_C * sqrtf(s);
}

// ---------------- encoder (r11 structure) + fused candidate prefilter --------
__global__ __launch_bounds__(256, 2) void k_encoder(const unsigned short* __restrict__ xcp,
                                                    const float* __restrict__ Wenc,
                                                    const float* __restrict__ benc,
                                                    float* __restrict__ pre,
                                                    const float* __restrict__ tau,
                                                    int* __restrict__ ccnt,
                                                    int* __restrict__ cidx,
                                                    float* __restrict__ cval) {
  __shared__ __align__(16) float Bs[4][64 * 32];   // 4 x 8 KB fp32
  const int tid = threadIdx.x;
  const int wm = tid >> 6, lane = tid & 63;
  const int l15 = lane & 15, kc = lane >> 4;

  int gRow[2], gCol[2], ldsL[2];
#pragma unroll
  for (int i = 0; i < 2; ++i) {
    int L = i * 4096 + tid * 16;
    int G = L ^ (((L >> 7) & 7) << 4);
    gRow[i] = G >> 7;
    gCol[i] = (G & 127) >> 2;
    ldsL[i] = L;
  }
  int bOff0[4], bOff1[4];
#pragma unroll
  for (int ni = 0; ni < 4; ++ni) {
    int row = ni * 16 + l15;
    int P = row * 128 + kc * 32;
    int sw = (row & 7) << 4;
    bOff0[ni] = P ^ sw;
    bOff1[ni] = (P + 16) ^ sw;
  }
  constexpr size_t A_MI = (size_t)T_SZ * NSK * 512;   // +16 b-rows (halfwords)

  for (int tile = 0; tile < 2; ++tile) {
    const int tileId = blockIdx.x + tile * 512;      // 0..1023
    const int t  = tileId >> 7;
    const int n0 = (tileId & 127) * 64;

    const float* bG = Wenc + ((size_t)t * DSAE + n0) * DIN;
    const unsigned short* aP =
        xcp + ((size_t)(wm * 4 * T_SZ + t) * NSK) * 512 + lane * 8;

    auto STAGE = [&](int buf, int s) {
#pragma unroll
      for (int i = 0; i < 2; ++i)
        gload_lds16(bG + (size_t)gRow[i] * DIN + s * 32 + gCol[i],
                    (char*)&Bs[0][0] + buf * 8192 + ldsL[i]);
    };

    f32x4 acc[4][4] = {};
    bf16x8 aA[4], aB[4];
    STAGE(0, 0);
#pragma unroll
    for (int mi = 0; mi < 4; ++mi)
      aA[mi] = *(const bf16x8*)(aP + mi * A_MI);
    STAGE(1, 1);

#define ENC_W6 asm volatile("s_waitcnt vmcnt(6)" ::: "memory")
#define ENC_W4 asm volatile("s_waitcnt vmcnt(4)" ::: "memory")
#define ENC_W0 asm volatile("s_waitcnt vmcnt(0)" ::: "memory")
#define ENC_STEP(u, PFB, PFA, WAITOP) do {                                   \
    if (PFB) STAGE(((u) + 2) & 3, s0 + (u) + 2);                             \
    if (PFA) {                                                               \
      const unsigned short* ap = aP + (size_t)(s0 + (u) + 1) * 512;          \
      _Pragma("unroll")                                                      \
      for (int mi = 0; mi < 4; ++mi) {                                       \
        bf16x8 v = *(const bf16x8*)(ap + mi * A_MI);                         \
        if ((u) % 2 == 0) aB[mi] = v; else aA[mi] = v;                       \
      }                                                                      \
    }                                                                        \
    __builtin_amdgcn_sched_barrier(0);                                       \
    WAITOP;                                                                  \
    __builtin_amdgcn_s_barrier();                                            \
    __builtin_amdgcn_sched_barrier(0);                                       \
    {                                                                        \
      const char* bb = (const char*)&Bs[0][0] + ((u) & 3) * 8192;            \
      _Pragma("unroll")                                                      \
      for (int ni = 0; ni < 4; ++ni) {                                       \
        f32x4 f0 = *(const f32x4*)(bb + bOff0[ni]);                          \
        f32x4 f1 = *(const f32x4*)(bb + bOff1[ni]);                          \
        union { uint32_t w[4]; bf16x8 h; } cvu;                              \
        cvu.w[0] = packtr(f0.x, f0.y); cvu.w[1] = packtr(f0.z, f0.w);        \
        cvu.w[2] = packtr(f1.x, f1.y); cvu.w[3] = packtr(f1.z, f1.w);        \
        _Pragma("unroll")                                                    \
        for (int mi = 0; mi < 4; ++mi)                                       \
          acc[mi][ni] = __builtin_amdgcn_mfma_f32_16x16x32_bf16(             \
              ((u) % 2 == 0) ? aA[mi] : aB[mi], cvu.h, acc[mi][ni], 0, 0, 0);\
      }                                                                      \
    }                                                                        \
  } while (0)

    int s0 = 0;
    for (int g = 0; g < 5; ++g, s0 += 4) {
      ENC_STEP(0, true, true, ENC_W6); ENC_STEP(1, true, true, ENC_W6);
      ENC_STEP(2, true, true, ENC_W6); ENC_STEP(3, true, true, ENC_W6);
    }
    ENC_STEP(0, true, true, ENC_W6);  ENC_STEP(1, true, true, ENC_W6);
    ENC_STEP(2, false, true, ENC_W4); ENC_STEP(3, false, false, ENC_W0);
#undef ENC_STEP
#undef ENC_W6
#undef ENC_W4
#undef ENC_W0

    // preload this thread's 16 row-taus
    float tv[4][4];
#pragma unroll
    for (int mi = 0; mi < 4; ++mi)
#pragma unroll
      for (int j = 0; j < 4; ++j)
        tv[mi][j] = tau[(wm * 64 + mi * 16 + kc * 4 + j) * T_SZ + t];

    // epilogue: write pre + push candidates >= tau_r
#pragma unroll
    for (int ni = 0; ni < 4; ++ni) {
      const int col = n0 + ni * 16 + l15;
      const float bias = benc[(size_t)t * DSAE + col];
#pragma unroll
      for (int mi = 0; mi < 4; ++mi) {
        const int rbase = wm * 64 + mi * 16 + kc * 4;
#pragma unroll
        for (int j = 0; j < 4; ++j) {
          const float v = acc[mi][ni][j] + bias;
          const int rr = (rbase + j) * T_SZ + t;
          pre[(size_t)rr * DSAE + col] = v;
          if (v >= tv[mi][j]) {
            int pos = atomicAdd(&ccnt[rr], 1);
            if (pos < CFCAP) {
              cidx[(size_t)rr * CFCAP + pos] = col;
              cval[(size_t)rr * CFCAP + pos] = v;
            }
          }
        }
      }
    }
    if (tile == 0) __syncthreads();
  }
}

// ---------------- top-k select: fused-candidate fast path + full fallback ----
__global__ __launch_bounds__(256) void k_select(const float* __restrict__ xc,
                                                const float* __restrict__ Wenc,
                                                const float* __restrict__ benc,
                                                float* u,   // pre in, u out
                                                int* __restrict__ sel_idx,
                                                float* __restrict__ sel_val,
                                                const float* __restrict__ tau,
                                                const int* __restrict__ ccnt,
                                                const int* __restrict__ cidx,
                                                const float* __restrict__ cval) {
  const int r = blockIdx.x, t = r & (T_SZ - 1);
  __shared__ float sp[DSAE];     // 32 KB (fallback row buffer)
  __shared__ float redf[4], redf2[4];
  __shared__ int   redi[4];
  __shared__ float cv[CFCAP]; __shared__ int ci[CFCAP];
  __shared__ float sv[CFCAP]; __shared__ int si[CFCAP];
  __shared__ float rv[RCAP];  __shared__ int ri[RCAP];
  __shared__ double rd[RCAP];
  __shared__ double xd[DIN];
  __shared__ int s_n, s_nR, s_A, s_nW;
  const int tid = threadIdx.x, lane = tid & 63, w = tid >> 6;
  float* urow = u + (size_t)r * DSAE;

  const int cnt = ccnt[r];
  const float taur = tau[r];
  bool tryFast = (cnt >= KSEL && cnt <= CFCAP);
  bool usedFast = false;
  float th = taur;
  int n = 0;
  float v32, wlo, whi;

  for (;;) {
    usedFast = tryFast;
    __syncthreads();                     // guard cv/ci/sv/si reuse
    if (tryFast) {
      n = cnt;
      th = taur;
      for (int i = tid; i < cnt; i += 256) {
        cv[i] = cval[(size_t)r * CFCAP + i];
        ci[i] = cidx[(size_t)r * CFCAP + i];
      }
    } else {
      // -------- full fallback: load row, sigma-seeded bisection, collect ----
      float s1 = 0.f, s2 = 0.f;
      for (int sgm = 0; sgm < DSAE / 256; ++sgm) {
        float v = urow[tid + sgm * 256];
        sp[tid + sgm * 256] = v;
        s1 += v; s2 = fmaf(v, v, s2);
      }
      for (int off = 32; off; off >>= 1) {
        s1 += __shfl_down(s1, off); s2 += __shfl_down(s2, off);
      }
      if (lane == 0) { redf[w] = s1; redf2[w] = s2; }
      __syncthreads();
      const float mean = (redf[0] + redf[1] + redf[2] + redf[3]) * (1.f / DSAE);
      const float var  = (redf2[0] + redf2[1] + redf2[2] + redf2[3]) * (1.f / DSAE) - mean * mean;
      const float sd   = sqrtf(fmaxf(var, 1e-20f));
      auto countGE = [&](float thv) -> int {
        int c = 0;
#pragma unroll
        for (int sgm = 0; sgm < DSAE / 256; ++sgm)
          c += (sp[tid + sgm * 256] >= thv) ? 1 : 0;
        for (int off = 32; off; off >>= 1) c += __shfl_down(c, off);
        __syncthreads();
        if (lane == 0) redi[w] = c;
        __syncthreads();
        return redi[0] + redi[1] + redi[2] + redi[3];
      };
      float tlo = mean + 2.0f * sd, thi2 = mean + 3.5f * sd;
      for (int it = 0; it < 8 && countGE(tlo) < KSEL; ++it) tlo -= sd;
      th = mean + 2.52f * sd;
      int c = countGE(th);
      for (int it = 0; it < 24 && (c < KSEL || c > CAND_CAP); ++it) {
        if (c > CAND_CAP) tlo = th; else thi2 = th;
        th = 0.5f * (tlo + thi2);
        c = countGE(th);
      }
      if (c < KSEL) { th = tlo; c = countGE(th); }
      if (tid == 0) s_n = 0;
      __syncthreads();
      for (int sgm = 0; sgm < DSAE / 256; ++sgm) {
        int i = tid + sgm * 256;
        float v = sp[i];
        if (v >= th) {
          int p = atomicAdd(&s_n, 1);
          if (p < CAND_CAP) { cv[p] = v; ci[p] = i; }
        }
      }
      __syncthreads();
      n = s_n < CAND_CAP ? s_n : CAND_CAP;
    }
    __syncthreads();

    // rank-sort desc (ties: lower idx first)
    if (tid < n) {
      float v = cv[tid]; int id = ci[tid];
      int rk = 0;
      for (int j = 0; j < n; ++j) {
        float vj = cv[j];
        rk += (vj > v || (vj == v && ci[j] < id)) ? 1 : 0;
      }
      sv[rk] = v; si[rk] = id;
    }
    __syncthreads();

    v32 = sv[KSEL - 1];
    wlo = v32 - EPS_W; whi = v32 + EPS_W;
    if (tid == 0) {
      int A = 0;
      while (A < KSEL - 1 && sv[A] > whi) ++A;
      s_A = A;
      int e = A;
      while (e < n && sv[e] >= wlo) ++e;
      s_nW = e - A;
    }
    __syncthreads();
    // fast-path validity: window must not dip below collection threshold
    if (usedFast && (wlo <= taur || s_nW > RCAP)) { tryFast = false; continue; }
    break;
  }

  const int A  = s_A;
  const int nW = s_nW < RCAP ? s_nW : RCAP;
  if (tid < nW) { rv[tid] = sv[A + tid]; ri[tid] = si[A + tid]; }
  if (tid == 0) s_nR = nW;
  __syncthreads();
  if (!usedFast && th > wlo) {   // fallback only: append sub-threshold window
    for (int sgm = 0; sgm < DSAE / 256; ++sgm) {
      int i = tid + sgm * 256;
      float v = sp[i];
      if (v >= wlo && v < th) {
        int p = atomicAdd(&s_nR, 1);
        if (p < RCAP) { rv[p] = v; ri[p] = i; }
      }
    }
  }
  __syncthreads();
  const int nR = s_nR < RCAP ? s_nR : RCAP;

  // fp64 refinement of boundary members
  if (nR >= 2) {
    for (int i = tid; i < DIN; i += 256) xd[i] = (double)xc[(size_t)r * DIN + i];
    __syncthreads();
    for (int j = w; j < nR; j += 4) {
      const int h = ri[j];
      const float* wrow = Wenc + ((size_t)t * DSAE + h) * DIN;
      double s = 0.0;
#pragma unroll
      for (int ss = 0; ss < DIN / 64; ++ss)
        s += xd[lane + 64 * ss] * (double)wrow[lane + 64 * ss];
      for (int off = 32; off; off >>= 1) s += __shfl_down(s, off);
      if (lane == 0) rd[j] = s + (double)benc[(size_t)t * DSAE + h];
    }
  } else if (nR == 1) {
    if (tid == 0) rd[0] = (double)rv[0];
  }
  __syncthreads();

  // u = zeros + scattered relu values
  for (int sgm = 0; sgm < DSAE / 256; ++sgm) urow[tid + sgm * 256] = 0.f;
  __syncthreads();

  if (tid < A) {
    float val = fmaxf(sv[tid], 0.f);
    urow[si[tid]] = val;
    sel_idx[(size_t)r * KSEL + tid] = si[tid];
    sel_val[(size_t)r * KSEL + tid] = val;
  }
  const int need = KSEL - A;
  if (tid < nR) {
    double v = rd[tid]; int id = ri[tid];
    int rk = 0;
    for (int j = 0; j < nR; ++j) {
      double vj = rd[j];
      rk += (vj > v || (vj == v && ri[j] < id)) ? 1 : 0;
    }
    if (rk < need) {
      float val = fmaxf((float)v, 0.f);
      urow[id] = val;
      sel_idx[(size_t)r * KSEL + A + rk] = id;
      sel_val[(size_t)r * KSEL + A + rk] = val;
    }
  }
}

// ---------------- direct sparse decoder (no transpose) + fused loss ----------
// Block = (d, t): stages Wdec[t][d][0..8192) = 32 KB FULLY CONTIGUOUS into
// LDS (linear 1 KB wave-loads); 256 threads each decode one b via 32 LDS
// gathers. Wdec read exactly once, linear, fp32 accuracy. 5 blocks/CU.
__global__ __launch_bounds__(256) void k_dec_direct(const float* __restrict__ Wdec,
                                                    const float* __restrict__ x,
                                                    const float* __restrict__ bdec,
                                                    const int* __restrict__ sel_idx,
                                                    const float* __restrict__ sel_val,
                                                    float* __restrict__ xhat,
                                                    float* __restrict__ loss) {
  __shared__ float row[DSAE];    // 32 KB
  __shared__ float rbuf[4];
  const int d = blockIdx.x, t = blockIdx.y;
  const int tid = threadIdx.x;
  const float* src = Wdec + ((size_t)t * DIN + d) * DSAE;
#pragma unroll
  for (int i = 0; i < 8; ++i)
    *(float4*)&row[i * 1024 + tid * 4] = *(const float4*)(src + i * 1024 + tid * 4);
  __syncthreads();

  const int r = tid * T_SZ + t;
  float acc = bdec[(size_t)t * DIN + d];
#pragma unroll 8
  for (int j = 0; j < KSEL; ++j) {
    const int h = sel_idx[(size_t)r * KSEL + j] & (DSAE - 1);
    acc = fmaf(sel_val[(size_t)r * KSEL + j], row[h], acc);
  }
  xhat[(size_t)r * DIN + d] = acc;
  const float e = acc - x[(size_t)r * DIN + d];
  float sq = e * e;
  for (int off = 32; off; off >>= 1) sq += __shfl_down(sq, off);
  if ((tid & 63) == 0) rbuf[tid >> 6] = sq;
  __syncthreads();
  if (tid == 0)
    atomicAdd(loss, (rbuf[0] + rbuf[1] + rbuf[2] + rbuf[3]) * (1.0f / NROWS));
}

// ---------------- host ------------------------------------------------------
extern "C" void kernel_launch(void* const* d_in, const int* in_sizes, int n_in,
                              void* d_out, int out_size, void* d_ws, size_t ws_size,
                              hipStream_t stream) {
  const float* x    = (const float*)d_in[0];
  const float* Wenc = (const float*)d_in[1];
  const float* benc = (const float*)d_in[2];
  const float* Wdec = (const float*)d_in[3];
  const float* bdec = (const float*)d_in[4];

  float* out  = (float*)d_out;
  float* loss = out;
  float* xhat = out + 1;
  float* u    = out + 1 + (size_t)NROWS * DIN;  // (B,T,DSAE) == rows r

  float*          wsf  = (float*)d_ws;
  float*          xc   = wsf + OFF_XC;
  unsigned short* xcp  = (unsigned short*)(wsf + OFF_XCP);
  int*            sidx = (int*)(wsf + OFF_SIDX);
  float*          sval = wsf + OFF_SVAL;
  float*          tau  = wsf + OFF_TAU;
  int*            ccnt = (int*)(wsf + OFF_CCNT);
  int*            cidx = (int*)(wsf + OFF_CIDX);
  float*          cval = wsf + OFF_CVAL;

  k_xc<<<NROWS * DIN / (256 * 8), 256, 0, stream>>>(x, bdec, xc, xcp);
  k_tau<<<NROWS / 4, 256, 0, stream>>>(xc, tau, ccnt, loss);
  k_encoder<<<512, 256, 0, stream>>>(xcp, Wenc, benc, u, tau, ccnt, cidx, cval);
  k_select<<<NROWS, 256, 0, stream>>>(xc, Wenc, benc, u, sidx, sval,
                                      tau, ccnt, cidx, cval);
  k_dec_direct<<<dim3(DIN, T_SZ), 256, 0, stream>>>(Wdec, x, bdec, sidx, sval,
                                                    xhat, loss);
}

// Round 16
// 238.130 us; speedup vs baseline: 1.2268x; 1.1627x over previous
//
#include <hip/hip_runtime.h>
#include <cstdint>
#include <cstddef>

// ---------------- problem constants (fixed by setup_inputs; k==32 always) ----
constexpr int B_SZ  = 256;
constexpr int T_SZ  = 8;
constexpr int DIN   = 768;
constexpr int DSAE  = 8192;
constexpr int KSEL  = 32;
constexpr int NROWS = B_SZ * T_SZ;        // 2048 (row r = b*T + t)
constexpr int CAND_CAP = 64;
constexpr int RCAP  = 32;                 // boundary-window capacity
constexpr float EPS_W = 3.2e-4f;          // ~7 sigma of pre err (trunc-B + rne-A)
constexpr int NSK   = DIN / 32;           // 24 k-steps (A-pack granularity)
constexpr int NSS   = DIN / 64;           // 12 super-steps (B staging, BK=64)

// ---------------- workspace layout (units: 4-byte words) ---------------------
constexpr size_t XC_SZ    = (size_t)NROWS * DIN;            // 1,572,864 w
constexpr size_t OFF_XC   = 0;
constexpr size_t OFF_XCP  = OFF_XC + XC_SZ;                 // packed bf16 xc
constexpr size_t XCP_W    = XC_SZ / 2;
constexpr size_t OFF_SIDX = OFF_XCP + XCP_W;
constexpr size_t OFF_SVAL = OFF_SIDX + (size_t)NROWS * KSEL;
constexpr size_t OFF_BIG  = OFF_SVAL + (size_t)NROWS * KSEL;
constexpr size_t BIG_W    = (size_t)T_SZ * DSAE * DIN / 2;  // 25,165,824 w
constexpr size_t WS_FAST_WORDS = OFF_BIG + BIG_W;           // ~110 MB

typedef short bf16x8 __attribute__((ext_vector_type(8)));  // 8 bf16 = 4 VGPR
typedef float f32x4  __attribute__((ext_vector_type(4)));

__device__ inline unsigned rne1(float x) {
  unsigned u = __float_as_uint(x);
  return (u + 0x7FFFu + ((u >> 16) & 1u)) >> 16;
}
__device__ inline float bf16tof(unsigned short v) {
  return __uint_as_float((unsigned)v << 16);
}
__device__ inline unsigned packtr(float a, float b) {
  return (__float_as_uint(a) >> 16) | (__float_as_uint(b) & 0xFFFF0000u);
}
__device__ inline void gload_lds16(const void* g, void* l) {
  __builtin_amdgcn_global_load_lds(
      (const __attribute__((address_space(1))) void*)g,
      (__attribute__((address_space(3))) void*)l, 16, 0, 0);
}

// ---------------- tiny init --------------------------------------------------
__global__ void k_zero(float* p) { *p = 0.f; }

// ---------------- xc = x - b_dec ; also emit FRAGMENT-PACKED bf16 copy -------
__global__ __launch_bounds__(256) void k_xc(const float* __restrict__ x,
                                            const float* __restrict__ bdec,
                                            float* __restrict__ xc,
                                            unsigned short* __restrict__ xcp) {
  const int c = blockIdx.x * 256 + threadIdx.x;   // 0 .. 196607
  const int lane = c & 63;
  const int u = c >> 6;
  const int s  = u % NSK;
  const int tt = (u / NSK) & (T_SZ - 1);
  const int gm = u / (NSK * T_SZ);                // 0..15
  const int b  = gm * 16 + (lane & 15);
  const int k0 = s * 32 + (lane >> 4) * 8;
  const size_t rowOff = ((size_t)(b * T_SZ + tt)) * DIN + k0;
  float4 v0 = *(const float4*)(x + rowOff);
  float4 v1 = *(const float4*)(x + rowOff + 4);
  float4 d0 = *(const float4*)(bdec + tt * DIN + k0);
  float4 d1 = *(const float4*)(bdec + tt * DIN + k0 + 4);
  v0.x -= d0.x; v0.y -= d0.y; v0.z -= d0.z; v0.w -= d0.w;
  v1.x -= d1.x; v1.y -= d1.y; v1.z -= d1.z; v1.w -= d1.w;
  *(float4*)(xc + rowOff) = v0;
  *(float4*)(xc + rowOff + 4) = v1;
  uint4 p;
  p.x = rne1(v0.x) | (rne1(v0.y) << 16);
  p.y = rne1(v0.z) | (rne1(v0.w) << 16);
  p.z = rne1(v1.x) | (rne1(v1.y) << 16);
  p.w = rne1(v1.z) | (rne1(v1.w) << 16);
  *(uint4*)(xcp + (size_t)c * 8) = p;
}

// ---------------- encoder: pre = xc @ W_enc[t]^T + b_enc (bf16 MFMA) ---------
// r11 structure with ONE change: BK 32->64. Each staging wave-instruction now
// covers 4 segments of 256 B (vs 8x128 B) -- tests the segments-per-
//-instruction rate model (all ~2 TB/s kernels had >=8 small segs/instr).
// B-tile/super-step = 64 rows x 256 B = 16 KB, staged by 4 gload_lds/thread
// with 16-slot XOR swizzle (slot ^= row&15); quad-buffered (64 KB LDS),
// counted vmcnt W16/W12/W8/W0 over 12 ops/step; raw s_barrier per step.
// A-frags per k-step from fragment-packed xcp (1 KB linear loads, L2-hot).
// Tile 256x64, 4 waves; grid 512, 2 tiles/block (2 blocks/CU balanced).
__global__ __launch_bounds__(256, 2) void k_encoder(const unsigned short* __restrict__ xcp,
                                                    const float* __restrict__ Wenc,
                                                    const float* __restrict__ benc,
                                                    float* __restrict__ pre) {
  __shared__ __align__(16) float Bs[4][64 * 64];   // 4 x 16 KB fp32
  const int tid = threadIdx.x;
  const int wm = tid >> 6, lane = tid & 63;
  const int l15 = lane & 15, kc = lane >> 4;

  // staging geometry: LDS byte L (0..16383) holds global (row, slotG) where
  // row = L>>8, slot = (L>>4)&15, slotG = slot ^ (row&15). Wave-instruction
  // covers 4 rows x 256 B (permuted 16 B chunks within each row's 256 B).
  int gOffF[4], ldsL[4];
#pragma unroll
  for (int i = 0; i < 4; ++i) {
    int L = i * 4096 + tid * 16;
    int row = L >> 8;
    int slot = (L >> 4) & 15;
    int slotG = slot ^ (row & 15);
    gOffF[i] = row * DIN + slotG * 4;   // + ss*64 floats at stage time
    ldsL[i] = L;
  }
  // frag-read byte offsets (within one 16 KB buffer): sub = k-half of BK=64
  int bOff0[2][4], bOff1[2][4];
#pragma unroll
  for (int sub = 0; sub < 2; ++sub)
#pragma unroll
    for (int ni = 0; ni < 4; ++ni) {
      int row = ni * 16 + l15;
      int sb = sub * 8 + kc * 2;
      bOff0[sub][ni] = row * 256 + (((sb + 0) ^ (row & 15)) << 4);
      bOff1[sub][ni] = row * 256 + (((sb + 1) ^ (row & 15)) << 4);
    }
  constexpr size_t A_MI = (size_t)T_SZ * NSK * 512;   // +16 b-rows (halfwords)

  for (int tile = 0; tile < 2; ++tile) {
    const int tileId = blockIdx.x + tile * 512;      // 0..1023
    const int t  = tileId >> 7;
    const int n0 = (tileId & 127) * 64;

    const float* bG = Wenc + ((size_t)t * DSAE + n0) * DIN;
    const unsigned short* aP =
        xcp + ((size_t)(wm * 4 * T_SZ + t) * NSK) * 512 + lane * 8;

    auto STAGE = [&](int buf, int ss) {
#pragma unroll
      for (int i = 0; i < 4; ++i)
        gload_lds16(bG + gOffF[i] + ss * 64,
                    (char*)&Bs[0][0] + buf * 16384 + ldsL[i]);
    };

    f32x4 acc[4][4] = {};
    bf16x8 aA[2][4], aB[2][4];

    // prologue: B(0) 4, A(0) 8, B(1) 4 in flight (16 vmem ops)
    STAGE(0, 0);
#pragma unroll
    for (int sub = 0; sub < 2; ++sub)
#pragma unroll
      for (int mi = 0; mi < 4; ++mi)
        aA[sub][mi] = *(const bf16x8*)(aP + sub * 512 + mi * A_MI);
    STAGE(1, 1);

#define ENC_W16 asm volatile("s_waitcnt vmcnt(16)" ::: "memory")
#define ENC_W12 asm volatile("s_waitcnt vmcnt(12)" ::: "memory")
#define ENC_W8  asm volatile("s_waitcnt vmcnt(8)" ::: "memory")
#define ENC_W0  asm volatile("s_waitcnt vmcnt(0)" ::: "memory")
// u = 0..3 within group; super-step = s0+u (s0 % 4 == 0); buffer = u&3.
#define ENC_STEP(u, PFB, PFA, WAITOP) do {                                   \
    if (PFB) STAGE(((u) + 2) & 3, s0 + (u) + 2);                             \
    if (PFA) {                                                               \
      const unsigned short* ap = aP + (size_t)(2 * (s0 + (u) + 1)) * 512;    \
      _Pragma("unroll")                                                      \
      for (int sub = 0; sub < 2; ++sub)                                      \
      _Pragma("unroll")                                                      \
      for (int mi = 0; mi < 4; ++mi) {                                       \
        bf16x8 v = *(const bf16x8*)(ap + sub * 512 + mi * A_MI);             \
        if ((u) % 2 == 0) aB[sub][mi] = v; else aA[sub][mi] = v;             \
      }                                                                      \
    }                                                                        \
    __builtin_amdgcn_sched_barrier(0);                                       \
    WAITOP;                                                                  \
    __builtin_amdgcn_s_barrier();                                            \
    __builtin_amdgcn_sched_barrier(0);                                       \
    {                                                                        \
      const char* bb = (const char*)&Bs[0][0] + ((u) & 3) * 16384;           \
      _Pragma("unroll")                                                      \
      for (int sub = 0; sub < 2; ++sub)                                      \
      _Pragma("unroll")                                                      \
      for (int ni = 0; ni < 4; ++ni) {                                       \
        f32x4 f0 = *(const f32x4*)(bb + bOff0[sub][ni]);                     \
        f32x4 f1 = *(const f32x4*)(bb + bOff1[sub][ni]);                     \
        union { uint32_t w[4]; bf16x8 h; } cvu;                              \
        cvu.w[0] = packtr(f0.x, f0.y); cvu.w[1] = packtr(f0.z, f0.w);        \
        cvu.w[2] = packtr(f1.x, f1.y); cvu.w[3] = packtr(f1.z, f1.w);        \
        _Pragma("unroll")                                                    \
        for (int mi = 0; mi < 4; ++mi)                                       \
          acc[mi][ni] = __builtin_amdgcn_mfma_f32_16x16x32_bf16(             \
              ((u) % 2 == 0) ? aA[sub][mi] : aB[sub][mi], cvu.h,             \
              acc[mi][ni], 0, 0, 0);                                         \
      }                                                                      \
    }                                                                        \
  } while (0)

    int s0 = 0;
    ENC_STEP(0, true, true, ENC_W16); ENC_STEP(1, true, true, ENC_W12);
    ENC_STEP(2, true, true, ENC_W12); ENC_STEP(3, true, true, ENC_W12);
    s0 = 4;
    ENC_STEP(0, true, true, ENC_W12); ENC_STEP(1, true, true, ENC_W12);
    ENC_STEP(2, true, true, ENC_W12); ENC_STEP(3, true, true, ENC_W12);
    s0 = 8;
    ENC_STEP(0, true, true, ENC_W12); ENC_STEP(1, true, true, ENC_W12);
    ENC_STEP(2, false, true, ENC_W8); ENC_STEP(3, false, false, ENC_W0);
#undef ENC_STEP
#undef ENC_W16
#undef ENC_W12
#undef ENC_W8
#undef ENC_W0

    // epilogue: C/D layout col=lane&15, row=(lane>>4)*4+reg
#pragma unroll
    for (int ni = 0; ni < 4; ++ni) {
      const int col = n0 + ni * 16 + l15;
      const float bias = benc[(size_t)t * DSAE + col];
#pragma unroll
      for (int mi = 0; mi < 4; ++mi) {
        const int rbase = wm * 64 + mi * 16 + kc * 4;
#pragma unroll
        for (int j = 0; j < 4; ++j)
          pre[((size_t)(rbase + j) * T_SZ + t) * DSAE + col] = acc[mi][ni][j] + bias;
      }
    }
    if (tile == 0) __syncthreads();   // tile boundary: full drain + barrier
  }
}

// ---------------- fused top-k select -----------------------------------------
__global__ __launch_bounds__(256) void k_select(const float* __restrict__ xc,
                                                const float* __restrict__ Wenc,
                                                const float* __restrict__ benc,
                                                float* u,   // pre in, u out (aliased)
                                                int* __restrict__ sel_idx,
                                                float* __restrict__ sel_val) {
  const int r = blockIdx.x, t = r & (T_SZ - 1);
  __shared__ float sp[DSAE];     // 32 KB
  __shared__ float redf[4], redf2[4];
  __shared__ int   redi[4];
  __shared__ float cv[CAND_CAP]; __shared__ int ci[CAND_CAP];
  __shared__ float sv[CAND_CAP]; __shared__ int si[CAND_CAP];
  __shared__ float rv[RCAP];     __shared__ int ri[RCAP];
  __shared__ double rd[RCAP];
  __shared__ double xd[DIN];     // 6 KB
  __shared__ int   s_n, s_nR, s_A, s_nW;
  const int tid = threadIdx.x, lane = tid & 63, w = tid >> 6;
  float* urow = u + (size_t)r * DSAE;

  float s1 = 0.f, s2 = 0.f;
  for (int sgm = 0; sgm < DSAE / 256; ++sgm) {
    float v = urow[tid + sgm * 256];
    sp[tid + sgm * 256] = v;
    s1 += v; s2 = fmaf(v, v, s2);
  }
  for (int off = 32; off; off >>= 1) {
    s1 += __shfl_down(s1, off); s2 += __shfl_down(s2, off);
  }
  if (lane == 0) { redf[w] = s1; redf2[w] = s2; }
  __syncthreads();
  const float mean = (redf[0] + redf[1] + redf[2] + redf[3]) * (1.f / DSAE);
  const float var  = (redf2[0] + redf2[1] + redf2[2] + redf2[3]) * (1.f / DSAE) - mean * mean;
  const float sd   = sqrtf(fmaxf(var, 1e-20f));

  auto countGE = [&](float th) -> int {
    int c = 0;
#pragma unroll
    for (int sgm = 0; sgm < DSAE / 256; ++sgm)
      c += (sp[tid + sgm * 256] >= th) ? 1 : 0;
    for (int off = 32; off; off >>= 1) c += __shfl_down(c, off);
    __syncthreads();
    if (lane == 0) redi[w] = c;
    __syncthreads();
    return redi[0] + redi[1] + redi[2] + redi[3];
  };

  float tlo = mean + 2.0f * sd, thi = mean + 3.5f * sd;
  for (int it = 0; it < 8 && countGE(tlo) < KSEL; ++it) tlo -= sd;
  float th = mean + 2.52f * sd;
  int c = countGE(th);
  for (int it = 0; it < 24 && (c < KSEL || c > CAND_CAP); ++it) {
    if (c > CAND_CAP) tlo = th; else thi = th;
    th = 0.5f * (tlo + thi);
    c = countGE(th);
  }
  if (c < KSEL) { th = tlo; c = countGE(th); }

  if (tid == 0) s_n = 0;
  __syncthreads();
  for (int sgm = 0; sgm < DSAE / 256; ++sgm) {
    int i = tid + sgm * 256;
    float v = sp[i];
    if (v >= th) {
      int p = atomicAdd(&s_n, 1);
      if (p < CAND_CAP) { cv[p] = v; ci[p] = i; }
    }
  }
  __syncthreads();
  const int n = s_n < CAND_CAP ? s_n : CAND_CAP;

  if (tid < n) {
    float v = cv[tid]; int id = ci[tid];
    int rk = 0;
    for (int j = 0; j < n; ++j) {
      float vj = cv[j];
      rk += (vj > v || (vj == v && ci[j] < id)) ? 1 : 0;
    }
    sv[rk] = v; si[rk] = id;
  }
  __syncthreads();

  const float v32 = sv[KSEL - 1];
  const float wlo = v32 - EPS_W, whi = v32 + EPS_W;
  if (tid == 0) {
    int A = 0;
    while (A < KSEL - 1 && sv[A] > whi) ++A;
    s_A = A;
    int e = A;
    while (e < n && sv[e] >= wlo) ++e;
    s_nW = e - A;
  }
  __syncthreads();
  const int A  = s_A;
  const int nW = s_nW < RCAP ? s_nW : RCAP;
  if (tid < nW) { rv[tid] = sv[A + tid]; ri[tid] = si[A + tid]; }
  if (tid == 0) s_nR = nW;
  __syncthreads();
  if (th > wlo) {
    for (int sgm = 0; sgm < DSAE / 256; ++sgm) {
      int i = tid + sgm * 256;
      float v = sp[i];
      if (v >= wlo && v < th) {
        int p = atomicAdd(&s_nR, 1);
        if (p < RCAP) { rv[p] = v; ri[p] = i; }
      }
    }
  }
  __syncthreads();
  const int nR = s_nR < RCAP ? s_nR : RCAP;

  if (nR >= 2) {
    for (int i = tid; i < DIN; i += 256) xd[i] = (double)xc[(size_t)r * DIN + i];
    __syncthreads();
    for (int j = w; j < nR; j += 4) {
      const int h = ri[j];
      const float* wrow = Wenc + ((size_t)t * DSAE + h) * DIN;
      double s = 0.0;
#pragma unroll
      for (int ss = 0; ss < DIN / 64; ++ss)
        s += xd[lane + 64 * ss] * (double)wrow[lane + 64 * ss];
      for (int off = 32; off; off >>= 1) s += __shfl_down(s, off);
      if (lane == 0) rd[j] = s + (double)benc[(size_t)t * DSAE + h];
    }
  } else if (nR == 1) {
    if (tid == 0) rd[0] = (double)rv[0];
  }
  __syncthreads();

  for (int sgm = 0; sgm < DSAE / 256; ++sgm) urow[tid + sgm * 256] = 0.f;
  __syncthreads();

  if (tid < A) {
    float val = fmaxf(sv[tid], 0.f);
    urow[si[tid]] = val;
    sel_idx[(size_t)r * KSEL + tid] = si[tid];
    sel_val[(size_t)r * KSEL + tid] = val;
  }
  const int need = KSEL - A;
  if (tid < nR) {
    double v = rd[tid]; int id = ri[tid];
    int rk = 0;
    for (int j = 0; j < nR; ++j) {
      double vj = rd[j];
      rk += (vj > v || (vj == v && ri[j] < id)) ? 1 : 0;
    }
    if (rk < need) {
      float val = fmaxf((float)v, 0.f);
      urow[id] = val;
      sel_idx[(size_t)r * KSEL + A + rk] = id;
      sel_val[(size_t)r * KSEL + A + rk] = val;
    }
  }
}

// ---------------- W_dec transpose: (T,DIN,DSAE) f32 -> (T,DSAE,DIN) bf16 -----
__global__ __launch_bounds__(256) void k_transpose(const float* __restrict__ W,
                                                   unsigned short* __restrict__ Wt) {
  __shared__ float s[32][33];
  const int t  = blockIdx.z;
  const int h0 = blockIdx.x * 32;
  const int d0 = blockIdx.y * 32;
  const int c  = threadIdx.x & 31, rr = threadIdx.x >> 5;
#pragma unroll
  for (int q = 0; q < 4; ++q) {
    int d = d0 + rr + q * 8;
    s[rr + q * 8][c] = W[((size_t)t * DIN + d) * DSAE + h0 + c];
  }
  __syncthreads();
#pragma unroll
  for (int q = 0; q < 4; ++q) {
    int h = h0 + rr + q * 8;
    Wt[((size_t)t * DSAE + h) * DIN + d0 + c] = (unsigned short)rne1(s[c][rr + q * 8]);
  }
}

// ---------------- sparse decoder + fused loss --------------------------------
template <bool TRANSPOSED>
__global__ __launch_bounds__(256) void k_decoder(const void* __restrict__ Wd_,
                                                 const float* __restrict__ x,
                                                 const float* __restrict__ bdec,
                                                 const int* __restrict__ sel_idx,
                                                 const float* __restrict__ sel_val,
                                                 float* __restrict__ xhat,
                                                 float* __restrict__ loss) {
  const int r = blockIdx.x, t = r & (T_SZ - 1);
  __shared__ int   si[KSEL];
  __shared__ float sv[KSEL];
  __shared__ float rbuf[4];
  const int tid = threadIdx.x;
  if (tid < KSEL) {
    si[tid] = sel_idx[(size_t)r * KSEL + tid] & (DSAE - 1);
    sv[tid] = sel_val[(size_t)r * KSEL + tid];
  }
  __syncthreads();

  float acc[3];
#pragma unroll
  for (int i = 0; i < 3; ++i) acc[i] = bdec[(size_t)t * DIN + tid + 256 * i];
#pragma unroll 4
  for (int j = 0; j < KSEL; ++j) {
    const int h = si[j];
    const float v = sv[j];
    if (TRANSPOSED) {
      const unsigned short* wrow =
          (const unsigned short*)Wd_ + ((size_t)t * DSAE + h) * DIN;
#pragma unroll
      for (int i = 0; i < 3; ++i)
        acc[i] = fmaf(v, bf16tof(wrow[tid + 256 * i]), acc[i]);
    } else {
      const float* Wd = (const float*)Wd_;
#pragma unroll
      for (int i = 0; i < 3; ++i)
        acc[i] = fmaf(v, Wd[((size_t)t * DIN + tid + 256 * i) * DSAE + h], acc[i]);
    }
  }
  float sq = 0.f;
#pragma unroll
  for (int i = 0; i < 3; ++i) {
    const int d = tid + 256 * i;
    const float xv = x[(size_t)r * DIN + d];
    xhat[(size_t)r * DIN + d] = acc[i];
    const float e = acc[i] - xv;
    sq = fmaf(e, e, sq);
  }
  for (int off = 32; off; off >>= 1) sq += __shfl_down(sq, off);
  if ((tid & 63) == 0) rbuf[tid >> 6] = sq;
  __syncthreads();
  if (tid == 0)
    atomicAdd(loss, (rbuf[0] + rbuf[1] + rbuf[2] + rbuf[3]) * (1.0f / NROWS));
}

// ---------------- host ------------------------------------------------------
extern "C" void kernel_launch(void* const* d_in, const int* in_sizes, int n_in,
                              void* d_out, int out_size, void* d_ws, size_t ws_size,
                              hipStream_t stream) {
  const float* x    = (const float*)d_in[0];
  const float* Wenc = (const float*)d_in[1];
  const float* benc = (const float*)d_in[2];
  const float* Wdec = (const float*)d_in[3];
  const float* bdec = (const float*)d_in[4];

  float* out  = (float*)d_out;
  float* loss = out;
  float* xhat = out + 1;
  float* u    = out + 1 + (size_t)NROWS * DIN;  // (B,T,DSAE) == rows r

  float*          wsf  = (float*)d_ws;
  float*          xc   = wsf + OFF_XC;
  unsigned short* xcp  = (unsigned short*)(wsf + OFF_XCP);
  int*            sidx = (int*)(wsf + OFF_SIDX);
  float*          sval = wsf + OFF_SVAL;
  unsigned short* big  = (unsigned short*)(wsf + OFF_BIG);  // wt (decoder)
  const bool fast = ws_size >= WS_FAST_WORDS * sizeof(float);

  k_zero<<<1, 1, 0, stream>>>(loss);
  k_xc<<<NROWS * DIN / (256 * 8), 256, 0, stream>>>(x, bdec, xc, xcp);
  k_encoder<<<512, 256, 0, stream>>>(xcp, Wenc, benc, u);
  k_select<<<NROWS, 256, 0, stream>>>(xc, Wenc, benc, u, sidx, sval);
  if (fast) {
    k_transpose<<<dim3(DSAE / 32, DIN / 32, T_SZ), 256, 0, stream>>>(Wdec, big);
    k_decoder<true><<<NROWS, 256, 0, stream>>>(big, x, bdec, sidx, sval, xhat, loss);
  } else {
    k_decoder<false><<<NROWS, 256, 0, stream>>>(Wdec, x, bdec, sidx, sval, xhat, loss);
  }
}